// Round 1
// baseline (171.958 us; speedup 1.0000x reference)
//
#include <hip/hip_runtime.h>
#include <math.h>

#define BB 32
#define SV 4096
#define SQ 1152
#define DD 128
#define FD 96
#define NS 32                      // chunks over SV
#define RPC (SV / NS)              // 128 rows per chunk
#define LOG2E 1.44269504088896340f

// ---- workspace layout (float offsets) ----
// G:     [B,D,FD]  group-of-12 sums of q (raw-view rows)      393216
// Psum/Psumsq/Pmin/Pmax: [B,NS,D] partial v stats             4x131072
// Zpart: [B,NS,D,3] partial softmax denominators (overlays P*) 393216
// T,M:   [B,D,3] softmax scale (log2 units) and max-shift
// sv,qs,att0: [B,D];  li,A0,A0sq: [B];  ip: [B,FD]; bnA,bnB: [FD]
#define OFF_G    0
#define OFF_PS   393216
#define OFF_PSS  524288
#define OFF_PMN  655360
#define OFF_PMX  786432
#define OFF_Z    393216   // overlays P* (dead after k_finalize_stats)
#define OFF_T    917504
#define OFF_M    929792
#define OFF_SV   942080
#define OFF_QS   946176
#define OFF_ATT0 950272
#define OFF_LI   954368
#define OFF_A0   954400
#define OFF_A0S  954432
#define OFF_IP   954464
#define OFF_BNA  957536
#define OFF_BNB  957632

// K1: q -> G. One thread per group of 12 consecutive floats (pool groups of
// the raw q.view(b,d,sq) rows land on flat 12-float chunks).
__global__ void k_groups(const float* __restrict__ q, float* __restrict__ G) {
    int g = blockIdx.x * blockDim.x + threadIdx.x;   // 393216 total
    const float4* p = reinterpret_cast<const float4*>(q + (size_t)g * 12);
    float4 a = p[0], b = p[1], c = p[2];
    G[g] = ((a.x + a.y) + (a.z + a.w)) + ((b.x + b.y) + (b.z + b.w))
         + ((c.x + c.y) + (c.z + c.w));
}

// K2: v stats pass: per (b, chunk, d) partial sum/sumsq/min/max over 128 rows.
__global__ void k_vstats(const float* __restrict__ v, float* __restrict__ ws) {
    float* Psum = ws + OFF_PS;  float* Psumsq = ws + OFF_PSS;
    float* Pmin = ws + OFF_PMN; float* Pmax = ws + OFF_PMX;
    int b = blockIdx.x / NS, chunk = blockIdx.x % NS;
    int lane = threadIdx.x & 31, rowg = threadIdx.x >> 5;  // 8 rows in flight
    int d0 = lane * 4;
    const float* base = v + ((size_t)b * SV + (size_t)chunk * RPC) * DD;
    float s[4] = {0,0,0,0}, ss[4] = {0,0,0,0}, mn[4], mx[4];
#pragma unroll
    for (int j = 0; j < 4; j++) { mn[j] = INFINITY; mx[j] = -INFINITY; }
    for (int i = 0; i < RPC / 8; i++) {
        int r = rowg + 8 * i;
        float4 x = *reinterpret_cast<const float4*>(base + (size_t)r * DD + d0);
        float vv[4] = {x.x, x.y, x.z, x.w};
#pragma unroll
        for (int j = 0; j < 4; j++) {
            s[j] += vv[j]; ss[j] += vv[j] * vv[j];
            mn[j] = fminf(mn[j], vv[j]); mx[j] = fmaxf(mx[j], vv[j]);
        }
    }
    __shared__ float red[4][8][DD];
#pragma unroll
    for (int j = 0; j < 4; j++) {
        red[0][rowg][d0+j] = s[j];  red[1][rowg][d0+j] = ss[j];
        red[2][rowg][d0+j] = mn[j]; red[3][rowg][d0+j] = mx[j];
    }
    __syncthreads();
    int d = threadIdx.x;
    if (d < DD) {
        float a = 0, b2 = 0, c = INFINITY, e = -INFINITY;
#pragma unroll
        for (int r = 0; r < 8; r++) {
            a += red[0][r][d]; b2 += red[1][r][d];
            c = fminf(c, red[2][r][d]); e = fmaxf(e, red[3][r][d]);
        }
        size_t o = ((size_t)b * NS + chunk) * DD + d;
        Psum[o] = a; Psumsq[o] = b2; Pmin[o] = c; Pmax[o] = e;
    }
}

// K3: finalize stats per (b,d): qs row sums, sumq, softmax scale T (log2
// units) and shift M. One block per batch, 128 threads (d).
__global__ void k_finalize_stats(const float* __restrict__ ws_g,
                                 const float* __restrict__ hmat,
                                 const float* __restrict__ hbias,
                                 float* __restrict__ ws) {
    const float* Psum = ws + OFF_PS;  const float* Psumsq = ws + OFF_PSS;
    const float* Pmin = ws + OFF_PMN; const float* Pmax = ws + OFF_PMX;
    const float* G = ws_g + OFF_G;
    float* T = ws + OFF_T; float* M = ws + OFF_M;
    float* svb = ws + OFF_SV; float* qsb = ws + OFF_QS;
    int b = blockIdx.x, d = threadIdx.x;
    float sum = 0, sumsq = 0, mn = INFINITY, mx = -INFINITY;
    for (int c2 = 0; c2 < NS; c2++) {
        size_t o = ((size_t)b * NS + c2) * DD + d;
        sum += Psum[o]; sumsq += Psumsq[o];
        mn = fminf(mn, Pmin[o]); mx = fmaxf(mx, Pmax[o]);
    }
    float qsv = 0;
    const float* gp = G + ((size_t)b * DD + d) * FD;
    for (int f = 0; f < FD; f++) qsv += gp[f];
    qsb[b * DD + d] = qsv;
    svb[b * DD + d] = sum;
    __shared__ float lds[DD];
    __shared__ float hm_l[3];
    __shared__ float sumq_l;
    lds[d] = qsv; __syncthreads();
    for (int st = 64; st > 0; st >>= 1) { if (d < st) lds[d] += lds[d + st]; __syncthreads(); }
    if (d == 0) sumq_l = lds[0];
    if (d < 3) { float h = 0; for (int x = 0; x < FD; x++) h += hmat[d * FD + x]; hm_l[d] = h; }
    __syncthreads();
    float sumq = sumq_l;
    for (int c = 0; c < 3; c++) {
        float alpha = hm_l[c] * sumq;
        float hb = hbias[c];
        float n2 = alpha * alpha * sumsq + 2.f * alpha * hb * sum + (float)SV * hb * hb;
        float t = alpha / sqrtf(n2);
        float tl = t * LOG2E;                       // fold log2(e): exp(t*v)=exp2(tl*v)
        float Ml = (tl >= 0.f) ? tl * mx : tl * mn; // max_s(tl*v) for stability
        T[((size_t)b * DD + d) * 3 + c] = tl;
        M[((size_t)b * DD + d) * 3 + c] = Ml;
    }
}

// K4: Z pass: per (b,chunk,d,c) partial softmax denominators.
__global__ void k_zpass(const float* __restrict__ v, float* __restrict__ ws) {
    const float* T = ws + OFF_T; const float* M = ws + OFF_M;
    float* Zpart = ws + OFF_Z;
    int b = blockIdx.x / NS, chunk = blockIdx.x % NS;
    int lane = threadIdx.x & 31, rowg = threadIdx.x >> 5;
    int d0 = lane * 4;
    float t[4][3], m[4][3];
#pragma unroll
    for (int j = 0; j < 4; j++)
#pragma unroll
        for (int c = 0; c < 3; c++) {
            t[j][c] = T[((size_t)b * DD + d0 + j) * 3 + c];
            m[j][c] = M[((size_t)b * DD + d0 + j) * 3 + c];
        }
    float acc[4][3] = {};
    const float* base = v + ((size_t)b * SV + (size_t)chunk * RPC) * DD;
    for (int i = 0; i < RPC / 8; i++) {
        int r = rowg + 8 * i;
        float4 x = *reinterpret_cast<const float4*>(base + (size_t)r * DD + d0);
        float vv[4] = {x.x, x.y, x.z, x.w};
#pragma unroll
        for (int j = 0; j < 4; j++)
#pragma unroll
            for (int c = 0; c < 3; c++)
                acc[j][c] += exp2f(vv[j] * t[j][c] - m[j][c]);
    }
    __shared__ float red[8][384];
#pragma unroll
    for (int j = 0; j < 4; j++)
#pragma unroll
        for (int c = 0; c < 3; c++) red[rowg][(d0 + j) * 3 + c] = acc[j][c];
    __syncthreads();
    for (int t2 = threadIdx.x; t2 < 384; t2 += 256) {
        float a = 0;
#pragma unroll
        for (int r = 0; r < 8; r++) a += red[r][t2];
        Zpart[((size_t)b * NS + chunk) * 384 + t2] = a;
    }
}

// K5: finalize attention sums at s=0,1,2; per-batch scalars; ip[b,f].
__global__ void k_att(const float* __restrict__ v, float* __restrict__ ws) {
    const float* Zpart = ws + OFF_Z;
    const float* T = ws + OFF_T; const float* M = ws + OFF_M;
    const float* svb = ws + OFF_SV; const float* qsb = ws + OFF_QS;
    const float* G = ws + OFF_G;
    float* att0b = ws + OFF_ATT0; float* lib = ws + OFF_LI;
    float* A0b = ws + OFF_A0; float* A0sb = ws + OFF_A0S;
    float* ipb = ws + OFF_IP;
    int b = blockIdx.x, d = threadIdx.x;  // 128 threads
    float Z[3] = {0, 0, 0};
    for (int c2 = 0; c2 < NS; c2++) {
        const float* zp = Zpart + ((size_t)b * NS + c2) * 384 + d * 3;
        Z[0] += zp[0]; Z[1] += zp[1]; Z[2] += zp[2];
    }
    float t[3], m[3], vX[3];
    for (int c = 0; c < 3; c++) {
        t[c] = T[((size_t)b * DD + d) * 3 + c];
        m[c] = M[((size_t)b * DD + d) * 3 + c];
    }
    for (int X = 0; X < 3; X++) vX[X] = v[((size_t)b * SV + X) * DD + d];
    float att[3] = {0, 0, 0};
    for (int c = 0; c < 3; c++) {
        float rz = 1.0f / Z[c];
        for (int X = 0; X < 3; X++) att[X] += exp2f(vX[X] * t[c] - m[c]) * rz;
    }
    att0b[b * DD + d] = att[0];
    float qsv = qsb[b * DD + d], svv = svb[b * DD + d];
    __shared__ float red[DD];
    __shared__ float svl[DD];
    svl[d] = svv;
    float vals[5] = {svv, att[1] * qsv, att[2] * qsv, att[0], att[0] * att[0]};
    float out5[5];
    for (int r5 = 0; r5 < 5; r5++) {
        __syncthreads(); red[d] = vals[r5]; __syncthreads();
        for (int st = 64; st > 0; st >>= 1) { if (d < st) red[d] += red[d + st]; __syncthreads(); }
        out5[r5] = red[0];
    }
    if (d == 0) {
        float vsum = out5[0];
        lib[b] = vsum * out5[1] + vsum * out5[2];   // l1 + l2
        A0b[b] = out5[3]; A0sb[b] = out5[4];
    }
    __syncthreads();
    if (d < FD) {
        float ipv = 0;
        for (int k = 0; k < DD; k++) ipv += svl[k] * G[((size_t)b * DD + k) * FD + d];
        ipb[b * FD + d] = ipv * (1.0f / 12.0f);
    }
}

// K6: closed-form BatchNorm channel stats -> affine coefs per f.
__global__ void k_bnstats(const float* __restrict__ gamma, const float* __restrict__ beta,
                          float* __restrict__ ws) {
    const float* ipb = ws + OFF_IP; const float* A0b = ws + OFF_A0;
    const float* A0sb = ws + OFF_A0S; const float* lib = ws + OFF_LI;
    float* bnA = ws + OFF_BNA; float* bnB = ws + OFF_BNB;
    int f = threadIdx.x;
    if (f >= FD) return;
    double Sm = 0, Se2 = 0, Sl = 0;
    for (int b = 0; b < BB; b++) {
        double ip = ipb[b * FD + f], a0 = A0b[b], a0s = A0sb[b], l = lib[b];
        Sm += ip * a0;
        Se2 += ip * ip * a0s + 2.0 * ip * l * a0 + (double)DD * l * l;
        Sl += l;
    }
    double mean = Sm / ((double)BB * DD) + Sl / (double)BB;
    double var = Se2 / ((double)BB * DD) - mean * mean;
    double rstd = 1.0 / sqrt(var + 1e-5);
    float A = (float)rstd * gamma[f];
    bnA[f] = A; bnB[f] = beta[f] - (float)mean * A;
}

// K7: write output [B,FD,D].
__global__ void k_out(const float* __restrict__ ws, float* __restrict__ out) {
    const float* att0b = ws + OFF_ATT0; const float* ipb = ws + OFF_IP;
    const float* lib = ws + OFF_LI;
    const float* bnA = ws + OFF_BNA; const float* bnB = ws + OFF_BNB;
    int idx = blockIdx.x * blockDim.x + threadIdx.x;   // 393216
    int k = idx & (DD - 1);
    int bf = idx >> 7;
    int f = bf % FD;
    int b = bf / FD;
    out[idx] = (att0b[b * DD + k] * ipb[b * FD + f] + lib[b]) * bnA[f] + bnB[f];
}

extern "C" void kernel_launch(void* const* d_in, const int* in_sizes, int n_in,
                              void* d_out, int out_size, void* d_ws, size_t ws_size,
                              hipStream_t stream) {
    const float* q     = (const float*)d_in[0];
    const float* v     = (const float*)d_in[1];
    const float* hmat  = (const float*)d_in[2];
    const float* hbias = (const float*)d_in[3];
    const float* gamma = (const float*)d_in[4];
    const float* beta  = (const float*)d_in[5];
    float* out = (float*)d_out;
    float* ws = (float*)d_ws;

    k_groups<<<(BB * DD * FD) / 256, 256, 0, stream>>>(q, ws + OFF_G);
    k_vstats<<<BB * NS, 256, 0, stream>>>(v, ws);
    k_finalize_stats<<<BB, DD, 0, stream>>>(ws, hmat, hbias, ws);
    k_zpass<<<BB * NS, 256, 0, stream>>>(v, ws);
    k_att<<<BB, DD, 0, stream>>>(v, ws);
    k_bnstats<<<1, 128, 0, stream>>>(gamma, beta, ws);
    k_out<<<(BB * FD * DD) / 256, 256, 0, stream>>>(ws, out);
}

// Round 2
// 126.057 us; speedup vs baseline: 1.3641x; 1.3641x over previous
//
#include <hip/hip_runtime.h>
#include <math.h>

#define BB 32
#define SV 4096
#define SQ 1152
#define DD 128
#define FD 96
#define NS 32                      // chunks over SV
#define RPC (SV / NS)              // 128 rows per chunk
#define LOG2E 1.44269504088896340f

// ---- workspace layout (float offsets) ----
// G: [B,D,FD] group-of-12 sums of q        393216 floats
// P: [B,NS,6,D] partial v moments M1..M6   786432 floats
// att0:[B,D]  li/A0/A0s:[B]  ip:[B,FD]  bnA/bnB:[FD]
#define OFF_G    0
#define OFF_P    393216
#define OFF_ATT0 1179648
#define OFF_LI   1183744
#define OFF_A0   1183776
#define OFF_A0S  1183808
#define OFF_IP   1183840
#define OFF_BNA  1186912
#define OFF_BNB  1187008

// K1 (fused): blocks [0,1024): v -> moment partials; blocks [1024,2560): q -> G.
__global__ __launch_bounds__(256) void k_pass1(const float* __restrict__ q,
                                               const float* __restrict__ v,
                                               float* __restrict__ ws) {
    __shared__ float red[6][8][DD];   // 24 KB (v-branch only)
    if (blockIdx.x < 1024) {
        int b = blockIdx.x >> 5, chunk = blockIdx.x & 31;
        int lane = threadIdx.x & 31, rowg = threadIdx.x >> 5;   // 8 rows in flight
        int d0 = lane * 4;
        const float* base = v + ((size_t)b * SV + (size_t)chunk * RPC) * DD;
        float s1[4] = {}, s2[4] = {}, s3[4] = {}, s4[4] = {}, s5[4] = {}, s6[4] = {};
        for (int i = 0; i < RPC / 8; i++) {
            float4 x = *reinterpret_cast<const float4*>(base + (size_t)(rowg + 8 * i) * DD + d0);
            float vv[4] = {x.x, x.y, x.z, x.w};
#pragma unroll
            for (int j = 0; j < 4; j++) {
                float a = vv[j], a2 = a * a, a4 = a2 * a2;
                s1[j] += a;       s2[j] += a2;      s3[j] += a2 * a;
                s4[j] += a4;      s5[j] += a4 * a;  s6[j] += a4 * a2;
            }
        }
#pragma unroll
        for (int j = 0; j < 4; j++) {
            red[0][rowg][d0 + j] = s1[j]; red[1][rowg][d0 + j] = s2[j];
            red[2][rowg][d0 + j] = s3[j]; red[3][rowg][d0 + j] = s4[j];
            red[4][rowg][d0 + j] = s5[j]; red[5][rowg][d0 + j] = s6[j];
        }
        __syncthreads();
        for (int t = threadIdx.x; t < 6 * DD; t += 256) {
            int m = t >> 7, d = t & (DD - 1);
            float a = 0;
#pragma unroll
            for (int r = 0; r < 8; r++) a += red[m][r][d];
            ws[OFF_P + ((size_t)(b * NS + chunk) * 6 + m) * DD + d] = a;
        }
    } else {
        int g = (blockIdx.x - 1024) * 256 + threadIdx.x;   // 0..393215
        const float4* p = reinterpret_cast<const float4*>(q + (size_t)g * 12);
        float4 a = p[0], b4 = p[1], c = p[2];
        ws[OFF_G + g] = ((a.x + a.y) + (a.z + a.w)) + ((b4.x + b4.y) + (b4.z + b4.w))
                      + ((c.x + c.y) + (c.z + c.w));
    }
}

// K2: per-batch finalize. One block per b, 256 threads.
__global__ __launch_bounds__(256) void k_finalize(const float* __restrict__ v,
                                                  const float* __restrict__ hmat,
                                                  const float* __restrict__ hbias,
                                                  float* __restrict__ ws) {
    int b = blockIdx.x, tid = threadIdx.x;
    __shared__ float Gl[DD * 97];                 // padded: 96 % 32 == 0 would 64-way conflict
    __shared__ float qsl[DD], svl[DD];
    __shared__ float hm_l[3], hb_l[3];
    __shared__ float redc[10];
    __shared__ float sumq_sh;
    const float* Gb = ws + OFF_G + (size_t)b * DD * FD;
#pragma unroll
    for (int i = 0; i < 12; i++) {                // stage G[b] (12288 floats) coalesced
        int idx = (i * 256 + tid) * 4;
        float4 x = *reinterpret_cast<const float4*>(Gb + idx);
        float xv[4] = {x.x, x.y, x.z, x.w};
#pragma unroll
        for (int j = 0; j < 4; j++) {
            int e = idx + j, dd = e / 96, f = e - dd * 96;
            Gl[dd * 97 + f] = xv[j];
        }
    }
    if (tid >= 128 && tid < 131) {
        int c = tid - 128;
        float h = 0;
        for (int x2 = 0; x2 < FD; x2++) h += hmat[c * FD + x2];
        hm_l[c] = h; hb_l[c] = hbias[c];
    }
    __syncthreads();
    float M1 = 0, M2 = 0, M3 = 0, M4 = 0, M5 = 0, M6 = 0;
    if (tid < 128) {                               // moments reduction (coalesced over d)
        const float* P = ws + OFF_P;
#pragma unroll 4
        for (int ch = 0; ch < NS; ch++) {
            const float* p = P + (size_t)(b * NS + ch) * 6 * DD + tid;
            M1 += p[0];      M2 += p[DD];     M3 += p[2 * DD];
            M4 += p[3 * DD]; M5 += p[4 * DD]; M6 += p[5 * DD];
        }
        svl[tid] = M1;
    } else {
        int d = tid - 128;                         // qs row sums from LDS (conflict-free)
        float qs = 0;
#pragma unroll 8
        for (int f = 0; f < FD; f++) qs += Gl[d * 97 + f];
        qsl[d] = qs;
    }
    __syncthreads();
    if (tid < 64) {                                // sumq: single-wave shuffle reduce
        float x = qsl[tid] + qsl[tid + 64];
#pragma unroll
        for (int ofs = 32; ofs; ofs >>= 1) x += __shfl_xor(x, ofs, 64);
        if (tid == 0) sumq_sh = x;
    }
    __syncthreads();
    if (tid < 128) {
        float sumq = sumq_sh;
        float v0 = v[((size_t)b * SV + 0) * DD + tid];
        float v1 = v[((size_t)b * SV + 1) * DD + tid];
        float v2 = v[((size_t)b * SV + 2) * DD + tid];
        float att0 = 0, att1 = 0, att2 = 0;
#pragma unroll
        for (int c = 0; c < 3; c++) {
            float alpha = hm_l[c] * sumq, hb = hb_l[c];
            float n2 = alpha * alpha * M2 + 2.f * alpha * hb * M1 + (float)SV * hb * hb;
            float tt = alpha / sqrtf(n2);          // |tt*v| <= ~0.1 -> Taylor-safe
            float Z = (float)SV + tt * (M1 + tt * (0.5f * M2 + tt * ((1.f / 6.f) * M3
                    + tt * ((1.f / 24.f) * M4 + tt * ((1.f / 120.f) * M5
                    + tt * (1.f / 720.f) * M6)))));
            float rz = 1.f / Z, tl = tt * LOG2E;
            att0 += exp2f(v0 * tl) * rz;
            att1 += exp2f(v1 * tl) * rz;
            att2 += exp2f(v2 * tl) * rz;
        }
        ws[OFF_ATT0 + b * DD + tid] = att0;
        float qsv = qsl[tid];
        float vals[5] = {att0, att0 * att0, att1 * qsv, att2 * qsv, M1};
#pragma unroll
        for (int i = 0; i < 5; i++) {
            float x = vals[i];
#pragma unroll
            for (int ofs = 32; ofs; ofs >>= 1) x += __shfl_xor(x, ofs, 64);
            if ((tid & 63) == 0) redc[(tid >> 6) * 5 + i] = x;
        }
    }
    __syncthreads();
    if (tid == 0) {
        float a0 = redc[0] + redc[5], a0s = redc[1] + redc[6];
        float r1 = redc[2] + redc[7], r2 = redc[3] + redc[8], vs = redc[4] + redc[9];
        ws[OFF_A0 + b] = a0; ws[OFF_A0S + b] = a0s;
        ws[OFF_LI + b] = vs * (r1 + r2);           // l1 + l2
    }
    if (tid < FD) {                                // ip[b,f] GEMV from LDS
        float ip = 0;
#pragma unroll 8
        for (int k = 0; k < DD; k++) ip += svl[k] * Gl[k * 97 + tid];
        ws[OFF_IP + b * FD + tid] = ip * (1.0f / 12.0f);
    }
}

// K3: closed-form BatchNorm channel stats -> affine coefs per f.
__global__ void k_bnstats(const float* __restrict__ gamma, const float* __restrict__ beta,
                          float* __restrict__ ws) {
    const float* ipb = ws + OFF_IP; const float* A0b = ws + OFF_A0;
    const float* A0sb = ws + OFF_A0S; const float* lib = ws + OFF_LI;
    float* bnA = ws + OFF_BNA; float* bnB = ws + OFF_BNB;
    int f = threadIdx.x;
    if (f >= FD) return;
    double Sm = 0, Se2 = 0, Sl = 0;
#pragma unroll 4
    for (int b = 0; b < BB; b++) {
        double ip = ipb[b * FD + f], a0 = A0b[b], a0s = A0sb[b], l = lib[b];
        Sm += ip * a0;
        Se2 += ip * ip * a0s + 2.0 * ip * l * a0 + (double)DD * l * l;
        Sl += l;
    }
    double mean = Sm / ((double)BB * DD) + Sl / (double)BB;
    double var = Se2 / ((double)BB * DD) - mean * mean;
    double rstd = 1.0 / sqrt(var + 1e-5);
    float A = (float)rstd * gamma[f];
    bnA[f] = A; bnB[f] = beta[f] - (float)mean * A;
}

// K4: write output [B,FD,D].
__global__ void k_out(const float* __restrict__ ws, float* __restrict__ out) {
    const float* att0b = ws + OFF_ATT0; const float* ipb = ws + OFF_IP;
    const float* lib = ws + OFF_LI;
    const float* bnA = ws + OFF_BNA; const float* bnB = ws + OFF_BNB;
    int idx = blockIdx.x * blockDim.x + threadIdx.x;   // 393216
    int k = idx & (DD - 1);
    int bf = idx >> 7;
    int f = bf % FD;
    int b = bf / FD;
    out[idx] = (att0b[b * DD + k] * ipb[b * FD + f] + lib[b]) * bnA[f] + bnB[f];
}

extern "C" void kernel_launch(void* const* d_in, const int* in_sizes, int n_in,
                              void* d_out, int out_size, void* d_ws, size_t ws_size,
                              hipStream_t stream) {
    const float* q     = (const float*)d_in[0];
    const float* v     = (const float*)d_in[1];
    const float* hmat  = (const float*)d_in[2];
    const float* hbias = (const float*)d_in[3];
    const float* gamma = (const float*)d_in[4];
    const float* beta  = (const float*)d_in[5];
    float* out = (float*)d_out;
    float* ws = (float*)d_ws;

    k_pass1<<<2560, 256, 0, stream>>>(q, v, ws);
    k_finalize<<<BB, 256, 0, stream>>>(v, hmat, hbias, ws);
    k_bnstats<<<1, 128, 0, stream>>>(gamma, beta, ws);
    k_out<<<(BB * FD * DD) / 256, 256, 0, stream>>>(ws, out);
}